// Round 1
// baseline (619.626 us; speedup 1.0000x reference)
//
#include <hip/hip_runtime.h>
#include <stdint.h>

#define TK_F       4096
#define TK_WPB     4            // independent waves (rows) per block
#define TK_THREADS (TK_WPB * 64)
#define TK_NBINS   2048         // top-11-bit histogram
#define TK_CAP     256          // candidate capacity (threshold bin); ~68 expected, 23-sigma margin
#define TK_VPL     16           // uint4 loads per lane
#define TK_EPL     64           // elements per lane

// order-preserving float<->uint transforms
__device__ __forceinline__ unsigned int tk_f2u(unsigned int b) {
    return b ^ ((unsigned int)(((int)b) >> 31) | 0x80000000u);
}
__device__ __forceinline__ unsigned int tk_u2f(unsigned int u) {
    return u ^ ((~(unsigned int)(((int)u) >> 31)) | 0x80000000u);
}

__global__ __launch_bounds__(TK_THREADS, 4)
void tk_topk_mask(const float* __restrict__ x, const int* __restrict__ kp,
                  float* __restrict__ out, int B)
{
    // per-wave private state -> no __syncthreads in the whole kernel
    __shared__ uint4        hist4[TK_WPB][TK_NBINS / 4];
    __shared__ unsigned int cand[TK_WPB][TK_CAP];
    __shared__ unsigned int cnt[TK_WPB];

    const int lane = (int)(threadIdx.x & 63u);
    const int wid  = (int)(threadIdx.x >> 6);
    const int row  = blockIdx.x * TK_WPB + wid;
    if (row >= B) return;

    const unsigned int k = (unsigned int)kp[0];
    unsigned int* hw = (unsigned int*)hist4[wid];

    const unsigned int* xr   = (const unsigned int*)(x + (size_t)row * TK_F);
    unsigned int*       orow = (unsigned int*)(out + (size_t)row * TK_F);
    const uint4*        xv   = (const uint4*)xr;

    // issue the 16 coalesced row loads first; they stay in flight during the LDS clear
    unsigned int u[TK_EPL];
    #pragma unroll
    for (int v = 0; v < TK_VPL; ++v) {
        uint4 t = xv[lane + v * 64];
        u[v*4+0] = t.x; u[v*4+1] = t.y; u[v*4+2] = t.z; u[v*4+3] = t.w;
    }

    // clear this wave's histogram: 8 x ds_write_b128
    const uint4 z = make_uint4(0u, 0u, 0u, 0u);
    #pragma unroll
    for (int i = 0; i < TK_NBINS / 4 / 64; ++i)
        hist4[wid][lane + i * 64] = z;
    if (lane == 0) cnt[wid] = 0u;

    // transform + histogram. Transposed slot(b) = ((b&63)<<5)|(b>>6) so the
    // strided readback below is bank-conflict-free.
    #pragma unroll
    for (int e = 0; e < TK_EPL; ++e) {
        u[e] = tk_f2u(u[e]);
        const unsigned int b11 = u[e] >> 21;
        atomicAdd(&hw[((b11 & 63u) << 5) | (b11 >> 6)], 1u);
    }

    // per-lane block sum: lane owns bins [lane*32, lane*32+32)
    // slot(lane*32+j) = ((lane&1)<<10) + (j<<5) + (lane>>1)  -> stride-32 dwords, 2 lanes/bank
    const unsigned int sbase = ((unsigned int)(lane & 1) << 10) | ((unsigned int)lane >> 1);
    unsigned int s = 0;
    #pragma unroll
    for (int j = 0; j < 32; ++j)
        s += hw[sbase + ((unsigned int)j << 5)];

    // inclusive suffix sum of s across lanes (higher lane = higher bins)
    unsigned int acc = s;
    #pragma unroll
    for (int d = 1; d < 64; d <<= 1) {
        const unsigned int t = (unsigned int)__shfl_down((int)acc, (unsigned int)d, 64);
        if (lane + d < 64) acc += t;
    }
    const unsigned int above = acc - s;   // elements in lane-blocks strictly above mine

    // find the lane-block containing the k-th element
    const unsigned long long bal = __ballot((above < k) && (acc >= k));
    int b = -1;
    unsigned int cum = 0;
    if (bal != 0ull) {
        const int wl = __ffsll((unsigned long long)bal) - 1;
        const unsigned int A = (unsigned int)__shfl((int)above, wl, 64);
        // lanes 0..31 cooperatively fetch the winner's 32 bins (single ds_read)
        unsigned int hl = 0;
        if (lane < 32)
            hl = hw[(((unsigned int)(wl & 1)) << 10) + (((unsigned int)lane) << 5) + (((unsigned int)wl) >> 1)];
        // suffix sum within lanes 0..31 (bin wl*32+lane)
        unsigned int a2 = hl;
        #pragma unroll
        for (int d = 1; d < 32; d <<= 1) {
            const unsigned int t = (unsigned int)__shfl_down((int)a2, (unsigned int)d, 64);
            if (lane + d < 32) a2 += t;
        }
        const unsigned int run = A + (a2 - hl);  // strictly above bin (wl*32+lane)
        const unsigned long long bal2 =
            __ballot((lane < 32) && (run < k) && (run + hl >= k));
        const int wb = __ffsll((unsigned long long)bal2) - 1;
        b   = wl * 32 + wb;
        cum = (unsigned int)__shfl((int)run, wb, 64);
    }

    if (b < 0) {
        // k >= row length: pass everything through
        #pragma unroll
        for (int v = 0; v < TK_VPL; ++v) {
            uint4 t;
            t.x = tk_u2f(u[v*4+0]); t.y = tk_u2f(u[v*4+1]);
            t.z = tk_u2f(u[v*4+2]); t.w = tk_u2f(u[v*4+3]);
            ((uint4*)orow)[lane + v * 64] = t;
        }
        return;
    }

    // collect candidates whose top-11 bits == b
    const unsigned int bb = (unsigned int)b;
    #pragma unroll
    for (int e = 0; e < TK_EPL; ++e) {
        if ((u[e] >> 21) == bb) {
            const unsigned int p = atomicAdd(&cnt[wid], 1u);
            if (p < TK_CAP) cand[wid][p] = u[e];
        }
    }

    unsigned int L = cnt[wid];
    if (L > TK_CAP) L = TK_CAP;
    const unsigned int r = k - cum;       // 1-based rank needed inside bin b

    // O(L^2) rank select among candidates (L ~ 68); inner reads are LDS broadcasts
    unsigned int Tl = 0, gl = 0, el = 0;
    int found = 0;
    for (unsigned int j = (unsigned int)lane; j < L; j += 64u) {
        const unsigned int uj = cand[wid][j];
        unsigned int g = 0, eq = 0;
        for (unsigned int i = 0; i < L; ++i) {
            const unsigned int ui = cand[wid][i];
            g  += (ui > uj)  ? 1u : 0u;
            eq += (ui == uj) ? 1u : 0u;
        }
        if (g < r && g + eq >= r) { Tl = uj; gl = g; el = eq; found = 1; }
    }
    const unsigned long long bal3 = __ballot(found);
    const int wt = __ffsll((unsigned long long)bal3) - 1;
    const unsigned int T  = (unsigned int)__shfl((int)Tl, wt, 64);
    const unsigned int g0 = (unsigned int)__shfl((int)gl, wt, 64);
    const unsigned int e0 = (unsigned int)__shfl((int)el, wt, 64);
    const unsigned int re = r - g0;       // # equal-to-T elements to include
    const bool easy = (e0 == re);         // no tie straddling the cut (overwhelmingly common)

    // masked write-back (coalesced uint4 stores)
    #pragma unroll
    for (int v = 0; v < TK_VPL; ++v) {
        uint4 t;
        #pragma unroll
        for (int j = 0; j < 4; ++j) {
            const unsigned int uu = u[v*4 + j];
            unsigned int val = 0u;
            if (uu > T) {
                val = tk_u2f(uu);
            } else if (uu == T) {
                if (easy) {
                    val = tk_u2f(uu);
                } else {
                    // rare: duplicated value straddles the cut -> lowest indices win
                    const int idx = (lane + v * 64) * 4 + j;
                    unsigned int c2 = 0;
                    for (int i = 0; i < idx; ++i)
                        c2 += (tk_f2u(xr[i]) == T) ? 1u : 0u;
                    if (c2 < re) val = tk_u2f(uu);
                }
            }
            (&t.x)[j] = val;
        }
        ((uint4*)orow)[lane + v * 64] = t;
    }
}

extern "C" void kernel_launch(void* const* d_in, const int* in_sizes, int n_in,
                              void* d_out, int out_size, void* d_ws, size_t ws_size,
                              hipStream_t stream) {
    const float* x   = (const float*)d_in[0];
    const int*   kp  = (const int*)d_in[1];
    float*       out = (float*)d_out;
    const int B = in_sizes[0] / TK_F;
    hipLaunchKernelGGL(tk_topk_mask, dim3((B + TK_WPB - 1) / TK_WPB), dim3(TK_THREADS),
                       0, stream, x, kp, out, B);
}